// Round 15
// baseline (462.280 us; speedup 1.0000x reference)
//
#include <hip/hip_runtime.h>

typedef unsigned short u16;
typedef unsigned int u32;
typedef float f32x4 __attribute__((ext_vector_type(4)));
typedef __bf16 bf16x8 __attribute__((ext_vector_type(8)));

#define DEV static __device__ __forceinline__

DEV u16 f2bf(float f) {
  u32 u = __builtin_bit_cast(u32, f);
  u += 0x7fffu + ((u >> 16) & 1u);
  return (u16)(u >> 16);
}

DEV float bf2f(u16 v) {
  u32 u = ((u32)v) << 16;
  return __builtin_bit_cast(float, u);
}

DEV void gload_lds16(const void* g, void* l) {
  __builtin_amdgcn_global_load_lds(
      (const __attribute__((address_space(1))) u32*)g,
      (__attribute__((address_space(3))) u32*)l, 16, 0, 0);
}

// ---------------- fused preprocessing: cvt + 2 transposes + bias gather ----
__global__ __launch_bounds__(256) void prep(
    const float* __restrict__ x, u16* __restrict__ xbf, int n4,
    const float* __restrict__ qkv_w, u16* __restrict__ qkvwT,
    const float* __restrict__ proj_w, u16* __restrict__ projwT,
    const float* __restrict__ bias_table, const int* __restrict__ rel_idx,
    float* __restrict__ biasM) {
  __shared__ float tile[32][33];
  const int bid = blockIdx.x;
  if (bid < 2048) {
    int i = bid * 256 + threadIdx.x;
    for (; i < n4; i += 2048 * 256) {
      const float4 v = ((const float4*)x)[i];
      ushort4 o;
      o.x = f2bf(v.x); o.y = f2bf(v.y); o.z = f2bf(v.z); o.w = f2bf(v.w);
      ((ushort4*)xbf)[i] = o;
    }
  } else if (bid < 2048 + 1728 + 576) {
    const bool qk = bid < 2048 + 1728;
    const int b2 = qk ? bid - 2048 : bid - (2048 + 1728);
    const float* in = qk ? qkv_w : proj_w;
    u16* out = qk ? qkvwT : projwT;
    const int N = qk ? 2304 : 768;
    const int nbx = N >> 5;
    const int bx = b2 % nbx, by = b2 / nbx;
    const int tx = threadIdx.x & 31, ty = threadIdx.x >> 5;
#pragma unroll
    for (int j = 0; j < 4; ++j)
      tile[ty + 8 * j][tx] = in[(long)(by * 32 + ty + 8 * j) * N + bx * 32 + tx];
    __syncthreads();
#pragma unroll
    for (int j = 0; j < 4; ++j)
      out[(long)(bx * 32 + ty + 8 * j) * 768 + by * 32 + tx] = f2bf(tile[tx][ty + 8 * j]);
  } else {
    const int i = (bid - (2048 + 1728 + 576)) * 256 + threadIdx.x;
    if (i < 12 * 2401) {
      const int h = i / 2401, p = i - h * 2401;
      biasM[i] = bias_table[rel_idx[p] * 12 + h];
    }
  }
}

// ---------------- 256x256 deep-pipelined GEMM (QKV; best measured) --------
template <bool OUT_BF16>
__global__ __launch_bounds__(512, 2) void gemm256(
    const u16* __restrict__ A, const u16* __restrict__ BT,
    void* __restrict__ C, const float* __restrict__ bias,
    int M, int N, int K, int nbn) {
  __shared__ alignas(16) char lds[131072];
  const int t = threadIdx.x;
  const int w = t >> 6, l = t & 63, lr = l & 15, lhi = l >> 4;
  const int wr = w >> 2, wc = w & 3;

  const int nwg = gridDim.x;
  const int q = nwg >> 3, r = nwg & 7;
  const int xcd = blockIdx.x & 7, lid = blockIdx.x >> 3;
  const int swz = (xcd < r ? xcd * (q + 1) : r * (q + 1) + (xcd - r) * q) + lid;
  const int bm = swz / nbn, bn = swz % nbn;

  const int T = K >> 5;
  const long Kb = (long)K * 2;

  const int unswz = (l & 7) ^ (l >> 3);
  const int arow = 2 * (l >> 3) + (unswz >> 2);
  const int acolb = (unswz & 3) << 4;
  const char* gA0 = (const char*)A + (long)(bm * 256 + w * 32 + arow) * Kb + acolb;
  const char* gA1 = gA0 + 16 * Kb;
  const char* gB0 = (const char*)BT + (long)(bn * 256 + w * 32 + arow) * Kb + acolb;
  const char* gB1 = gB0 + 16 * Kb;
  const int ldA0 = w * 2048, ldA1 = w * 2048 + 1024;
  const int ldB0 = 16384 + w * 2048, ldB1 = 16384 + w * 2048 + 1024;

#define STAGE(tt)                               \
  {                                             \
    const int bb = ((tt) & 3) * 32768;          \
    const long ko = (long)(tt) * 64;            \
    gload_lds16(gA0 + ko, lds + bb + ldA0);     \
    gload_lds16(gA1 + ko, lds + bb + ldA1);     \
    gload_lds16(gB0 + ko, lds + bb + ldB0);     \
    gload_lds16(gB1 + ko, lds + bb + ldB1);     \
  }
#define BAR                                  \
  asm volatile("" ::: "memory");             \
  __builtin_amdgcn_s_barrier();              \
  asm volatile("" ::: "memory")

  const int rblk = ((((lr & 1) << 2) | lhi) ^ (lr >> 1));
  const int aoff0 = (wr * 64 + (lr >> 1)) * 128 + rblk * 16;
  const int boff0 = 16384 + (wc * 32 + (lr >> 1)) * 128 + rblk * 16;

  f32x4 acc[8][4];
#pragma unroll
  for (int m = 0; m < 8; ++m)
#pragma unroll
    for (int n = 0; n < 4; ++n) acc[m][n] = (f32x4){0.f, 0.f, 0.f, 0.f};
  bf16x8 afrX[4], bfrX[4], afrY[4], bfrY[4];

#define CLUSTER1(S)                                                        \
  __builtin_amdgcn_s_setprio(1);                                           \
  _Pragma("unroll") for (int m = 0; m < 4; ++m)                            \
      _Pragma("unroll") for (int n = 0; n < 4; ++n)                        \
          acc[m][n] = __builtin_amdgcn_mfma_f32_16x16x32_bf16(             \
              afr##S[m], bfr##S[n], acc[m][n], 0, 0, 0);                   \
  __builtin_amdgcn_s_setprio(0)
#define CLUSTER2(S)                                                        \
  __builtin_amdgcn_s_setprio(1);                                           \
  _Pragma("unroll") for (int m = 0; m < 4; ++m)                            \
      _Pragma("unroll") for (int n = 0; n < 4; ++n)                        \
          acc[m + 4][n] = __builtin_amdgcn_mfma_f32_16x16x32_bf16(         \
              afr2[m], bfr##S[n], acc[m + 4][n], 0, 0, 0);                 \
  __builtin_amdgcn_s_setprio(0)

#define BODY(kt, S, R)                                                     \
  {                                                                        \
    if ((kt) + 3 < T) STAGE((kt) + 3);                                     \
    const int bbc = ((kt) & 3) * 32768;                                    \
    const int nx = ((kt) + 1 < T) ? (kt) + 1 : (kt);                       \
    const int bbn = (nx & 3) * 32768;                                      \
    bf16x8 afr2[4];                                                        \
    _Pragma("unroll") for (int m = 0; m < 4; ++m)                          \
        afr2[m] = *(const bf16x8*)(lds + bbc + aoff0 + (m + 4) * 1024);    \
    CLUSTER1(S);                                                           \
    _Pragma("unroll") for (int n = 0; n < 4; ++n)                          \
        bfr##R[n] = *(const bf16x8*)(lds + bbn + boff0 + n * 1024);        \
    CLUSTER2(S);                                                           \
    _Pragma("unroll") for (int m = 0; m < 4; ++m)                          \
        afr##R[m] = *(const bf16x8*)(lds + bbn + aoff0 + m * 1024);        \
    if ((kt) + 3 < T) {                                                    \
      asm volatile("s_waitcnt vmcnt(4)" ::: "memory");                     \
    } else {                                                               \
      asm volatile("s_waitcnt vmcnt(0)" ::: "memory");                     \
    }                                                                      \
    BAR;                                                                   \
  }

  STAGE(0); STAGE(1); STAGE(2);
  asm volatile("s_waitcnt vmcnt(4)" ::: "memory");
  BAR;
#pragma unroll
  for (int n = 0; n < 4; ++n) bfrX[n] = *(const bf16x8*)(lds + boff0 + n * 1024);
#pragma unroll
  for (int m = 0; m < 4; ++m) afrX[m] = *(const bf16x8*)(lds + aoff0 + m * 1024);

  for (int i = 0; i < T / 2; ++i) {
    BODY(2 * i, X, Y);
    BODY(2 * i + 1, Y, X);
  }
#undef STAGE
#undef BODY

  const int row0 = bm * 256 + wr * 128 + 4 * lhi;
  const int col0 = bn * 256 + wc * 64 + lr;
  if (OUT_BF16) {
    u16* Cc = (u16*)C;
#pragma unroll
    for (int m = 0; m < 8; ++m)
#pragma unroll
      for (int rr = 0; rr < 4; ++rr) {
        const long row = row0 + m * 16 + rr;
#pragma unroll
        for (int n = 0; n < 4; ++n)
          Cc[row * N + col0 + n * 16] = f2bf(acc[m][n][rr]);
      }
  } else {
    float* Cf = (float*)C;
    float bv[4];
#pragma unroll
    for (int n = 0; n < 4; ++n) bv[n] = bias[col0 + n * 16];
#pragma unroll
    for (int m = 0; m < 8; ++m)
#pragma unroll
      for (int rr = 0; rr < 4; ++rr) {
        const long row = row0 + m * 16 + rr;
#pragma unroll
        for (int n = 0; n < 4; ++n)
          Cf[row * N + col0 + n * 16] = acc[m][n][rr] + bv[n];
      }
  }
#undef BAR
#undef CLUSTER1
#undef CLUSTER2
}

// ---------------- 128x128 GEMM (proj): same schedule, 2 blocks/CU ---------
// 4 waves (2x2), per-wave 64x64, acc[4][4]. LDS 16KB/buffer x4 = 64KB ->
// 2 blocks/CU: cross-block overlap hides the per-block barrier convoy, and
// grid 2352 kills the 588-block tail of the 256^2 version.
// Same swizzle (conflict-free) and depth-3 vmcnt(4) ping-pong as gemm256.
template <bool OUT_BF16>
__global__ __launch_bounds__(256, 2) void gemm128(
    const u16* __restrict__ A, const u16* __restrict__ BT,
    void* __restrict__ C, const float* __restrict__ bias,
    int M, int N, int K, int nbn) {
  __shared__ alignas(16) char lds[65536];
  const int t = threadIdx.x;
  const int w = t >> 6, l = t & 63, lr = l & 15, lhi = l >> 4;
  const int wr = w >> 1, wc = w & 1;

  const int nwg = gridDim.x;
  const int q = nwg >> 3, r = nwg & 7;
  const int xcd = blockIdx.x & 7, lid = blockIdx.x >> 3;
  const int swz = (xcd < r ? xcd * (q + 1) : r * (q + 1) + (xcd - r) * q) + lid;
  const int bm = swz / nbn, bn = swz % nbn;

  const int T = K >> 5;
  const long Kb = (long)K * 2;

  // per wave: 32 A-rows + 32 B-rows, 2+2 gload16/tile (identical constants)
  const int unswz = (l & 7) ^ (l >> 3);
  const int arow = 2 * (l >> 3) + (unswz >> 2);
  const int acolb = (unswz & 3) << 4;
  const char* gA0 = (const char*)A + (long)(bm * 128 + w * 32 + arow) * Kb + acolb;
  const char* gA1 = gA0 + 16 * Kb;
  const char* gB0 = (const char*)BT + (long)(bn * 128 + w * 32 + arow) * Kb + acolb;
  const char* gB1 = gB0 + 16 * Kb;
  const int ldA0 = w * 2048, ldA1 = w * 2048 + 1024;
  const int ldB0 = 8192 + w * 2048, ldB1 = 8192 + w * 2048 + 1024;

#define STAGE(tt)                               \
  {                                             \
    const int bb = ((tt) & 3) * 16384;          \
    const long ko = (long)(tt) * 64;            \
    gload_lds16(gA0 + ko, lds + bb + ldA0);     \
    gload_lds16(gA1 + ko, lds + bb + ldA1);     \
    gload_lds16(gB0 + ko, lds + bb + ldB0);     \
    gload_lds16(gB1 + ko, lds + bb + ldB1);     \
  }
#define BAR                                  \
  asm volatile("" ::: "memory");             \
  __builtin_amdgcn_s_barrier();              \
  asm volatile("" ::: "memory")

  const int rblk = ((((lr & 1) << 2) | lhi) ^ (lr >> 1));
  const int aoff0 = (wr * 32 + (lr >> 1)) * 128 + rblk * 16;         // + mt*1024
  const int boff0 = 8192 + (wc * 32 + (lr >> 1)) * 128 + rblk * 16;  // + nt*1024

  f32x4 acc[4][4];
#pragma unroll
  for (int m = 0; m < 4; ++m)
#pragma unroll
    for (int n = 0; n < 4; ++n) acc[m][n] = (f32x4){0.f, 0.f, 0.f, 0.f};
  bf16x8 afrX[2], bfrX[4], afrY[2], bfrY[4];

#define CLUSTER1(S)                                                        \
  __builtin_amdgcn_s_setprio(1);                                           \
  _Pragma("unroll") for (int m = 0; m < 2; ++m)                            \
      _Pragma("unroll") for (int n = 0; n < 4; ++n)                        \
          acc[m][n] = __builtin_amdgcn_mfma_f32_16x16x32_bf16(             \
              afr##S[m], bfr##S[n], acc[m][n], 0, 0, 0);                   \
  __builtin_amdgcn_s_setprio(0)
#define CLUSTER2(S)                                                        \
  __builtin_amdgcn_s_setprio(1);                                           \
  _Pragma("unroll") for (int m = 0; m < 2; ++m)                            \
      _Pragma("unroll") for (int n = 0; n < 4; ++n)                        \
          acc[m + 2][n] = __builtin_amdgcn_mfma_f32_16x16x32_bf16(         \
              afr2[m], bfr##S[n], acc[m + 2][n], 0, 0, 0);                 \
  __builtin_amdgcn_s_setprio(0)

#define BODY(kt, S, R)                                                     \
  {                                                                        \
    if ((kt) + 3 < T) STAGE((kt) + 3);                                     \
    const int bbc = ((kt) & 3) * 16384;                                    \
    const int nx = ((kt) + 1 < T) ? (kt) + 1 : (kt);                       \
    const int bbn = (nx & 3) * 16384;                                      \
    bf16x8 afr2[2];                                                        \
    _Pragma("unroll") for (int m = 0; m < 2; ++m)                          \
        afr2[m] = *(const bf16x8*)(lds + bbc + aoff0 + (m + 2) * 1024);    \
    CLUSTER1(S);                                                           \
    _Pragma("unroll") for (int n = 0; n < 4; ++n)                          \
        bfr##R[n] = *(const bf16x8*)(lds + bbn + boff0 + n * 1024);        \
    CLUSTER2(S);                                                           \
    _Pragma("unroll") for (int m = 0; m < 2; ++m)                          \
        afr##R[m] = *(const bf16x8*)(lds + bbn + aoff0 + m * 1024);        \
    if ((kt) + 3 < T) {                                                    \
      asm volatile("s_waitcnt vmcnt(4)" ::: "memory");                     \
    } else {                                                               \
      asm volatile("s_waitcnt vmcnt(0)" ::: "memory");                     \
    }                                                                      \
    BAR;                                                                   \
  }

  STAGE(0); STAGE(1); STAGE(2);
  asm volatile("s_waitcnt vmcnt(4)" ::: "memory");
  BAR;
#pragma unroll
  for (int n = 0; n < 4; ++n) bfrX[n] = *(const bf16x8*)(lds + boff0 + n * 1024);
#pragma unroll
  for (int m = 0; m < 2; ++m) afrX[m] = *(const bf16x8*)(lds + aoff0 + m * 1024);

  for (int i = 0; i < T / 2; ++i) {
    BODY(2 * i, X, Y);
    BODY(2 * i + 1, Y, X);
  }
#undef STAGE
#undef BODY
#undef BAR
#undef CLUSTER1
#undef CLUSTER2

  const int row0 = bm * 128 + wr * 64 + 4 * lhi;
  const int col0 = bn * 128 + wc * 64 + lr;
  if (OUT_BF16) {
    u16* Cc = (u16*)C;
#pragma unroll
    for (int m = 0; m < 4; ++m)
#pragma unroll
      for (int rr = 0; rr < 4; ++rr) {
        const long row = row0 + m * 16 + rr;
#pragma unroll
        for (int n = 0; n < 4; ++n)
          Cc[row * N + col0 + n * 16] = f2bf(acc[m][n][rr]);
      }
  } else {
    float* Cf = (float*)C;
    float bv[4];
#pragma unroll
    for (int n = 0; n < 4; ++n) bv[n] = bias[col0 + n * 16];
#pragma unroll
    for (int m = 0; m < 4; ++m)
#pragma unroll
      for (int rr = 0; rr < 4; ++rr) {
        const long row = row0 + m * 16 + rr;
#pragma unroll
        for (int n = 0; n < 4; ++n)
          Cf[row * N + col0 + n * 16] = acc[m][n][rr] + bv[n];
      }
  }
}

// ---------------- fused attention (r14: 2 barriers, wave-local epilogue) ---
__global__ __launch_bounds__(256) void attn_kernel(
    const u16* __restrict__ qkv,        // [B*49, 2304] bf16
    const float* __restrict__ prev,     // [B,12,49,49]
    const float* __restrict__ biasM,    // [12,49*49]
    float* __restrict__ prev_out,       // [B,12,49,49]
    u16* __restrict__ attn_out) {       // [B*49, 768] bf16
  __shared__ u16 Qs[64][72];   // Q -> P -> O (all wave-local transitions)
  __shared__ u16 Ks[64][72];
  __shared__ u16 VTs[64][72];
  __shared__ u16 SB[2432];     // prev+bias then scores, bf16

  const int bh = blockIdx.x;
  const int b = bh / 12, h = bh % 12;
  const int t = threadIdx.x, w = t >> 6, l = t & 63, lr = l & 15, lhi = l >> 4;

  const u16* base = qkv + (long)(b * 49) * 2304 + h * 64;
  for (int idx = t; idx < 49 * 16; idx += 256) {
    const int n = idx >> 4, c4 = (idx & 15) << 2;
    const u16* rp = base + (long)n * 2304;
    ushort4 qv = *(const ushort4*)(rp + c4);
    ushort4 kv = *(const ushort4*)(rp + 768 + c4);
    ushort4 vv = *(const ushort4*)(rp + 1536 + c4);
    *(ushort4*)&Qs[n][c4] = qv;
    *(ushort4*)&Ks[n][c4] = kv;
    VTs[c4 + 0][n] = vv.x;
    VTs[c4 + 1][n] = vv.y;
    VTs[c4 + 2][n] = vv.z;
    VTs[c4 + 3][n] = vv.w;
  }
  for (int idx = t; idx < 1024; idx += 256) {
    const int j = idx & 15;
    if (j) VTs[idx >> 4][48 + j] = 0;
  }

  float prevR[10], biasR[10];
  {
    const float* pv = prev + (long)bh * 2401;
    const float* bm = biasM + h * 2401;
#pragma unroll
    for (int k = 0; k < 10; ++k) {
      const int i = t + 256 * k;
      if (i < 2401) {
        prevR[k] = pv[i];
        biasR[k] = bm[i];
      }
    }
  }

  asm volatile("s_waitcnt lgkmcnt(0)" ::: "memory");
  __builtin_amdgcn_s_barrier();
  asm volatile("" ::: "memory");

  bf16x8 af0 = *(const bf16x8*)&Qs[16 * w + lr][lhi * 8];
  bf16x8 af1 = *(const bf16x8*)&Qs[16 * w + lr][32 + lhi * 8];
  f32x4 sacc[4];
#pragma unroll
  for (int tc = 0; tc < 4; ++tc) {
    sacc[tc] = (f32x4){0.f, 0.f, 0.f, 0.f};
    bf16x8 b0 = *(const bf16x8*)&Ks[16 * tc + lr][lhi * 8];
    bf16x8 b1 = *(const bf16x8*)&Ks[16 * tc + lr][32 + lhi * 8];
    sacc[tc] = __builtin_amdgcn_mfma_f32_16x16x32_bf16(af0, b0, sacc[tc], 0, 0, 0);
    sacc[tc] = __builtin_amdgcn_mfma_f32_16x16x32_bf16(af1, b1, sacc[tc], 0, 0, 0);
  }

  asm volatile("s_waitcnt vmcnt(0)" ::: "memory");
#pragma unroll
  for (int k = 0; k < 10; ++k) {
    const int i = t + 256 * k;
    if (i < 2401) SB[i] = f2bf(prevR[k] + biasR[k]);
  }
  asm volatile("s_waitcnt lgkmcnt(0)" ::: "memory");
  __builtin_amdgcn_s_barrier();
  asm volatile("" ::: "memory");

  u16 (*Ps)[72] = Qs;
  const int nrow0 = 16 * w + 4 * lhi;
  float rs[4];
#pragma unroll
  for (int r = 0; r < 4; ++r) {
    const int row = nrow0 + r;
    const bool rv = row < 49;
    float sv[4];
#pragma unroll
    for (int tc = 0; tc < 4; ++tc) {
      const int col = 16 * tc + lr;
      const bool valid = rv && (col < 49);
      const int sidx = (row < 49 ? row : 48) * 49 + (col < 49 ? col : 48);
      const float pb = bf2f(SB[sidx]);
      const float s = sacc[tc][r] * 0.125f + pb;
      if (valid) SB[sidx] = f2bf(s);
      sv[tc] = valid ? s : -INFINITY;
    }
    float mx = fmaxf(fmaxf(sv[0], sv[1]), fmaxf(sv[2], sv[3]));
#pragma unroll
    for (int off = 8; off; off >>= 1) mx = fmaxf(mx, __shfl_xor(mx, off, 16));
    float e[4], sum = 0.f;
#pragma unroll
    for (int tc = 0; tc < 4; ++tc) {
      e[tc] = __expf(sv[tc] - mx);
      sum += e[tc];
    }
#pragma unroll
    for (int off = 8; off; off >>= 1) sum += __shfl_xor(sum, off, 16);
    rs[r] = 1.0f / sum;
#pragma unroll
    for (int tc = 0; tc < 4; ++tc)
      Ps[row][16 * tc + lr] = rv ? f2bf(e[tc]) : (u16)0;
  }

  asm volatile("s_waitcnt lgkmcnt(0)" ::: "memory");
  __builtin_amdgcn_sched_barrier(0);

  bf16x8 pf0 = *(const bf16x8*)&Ps[16 * w + lr][lhi * 8];
  bf16x8 pf1 = *(const bf16x8*)&Ps[16 * w + lr][32 + lhi * 8];
  f32x4 oacc[4];
#pragma unroll
  for (int dc = 0; dc < 4; ++dc) {
    oacc[dc] = (f32x4){0.f, 0.f, 0.f, 0.f};
    bf16x8 v0 = *(const bf16x8*)&VTs[16 * dc + lr][lhi * 8];
    bf16x8 v1 = *(const bf16x8*)&VTs[16 * dc + lr][32 + lhi * 8];
    oacc[dc] = __builtin_amdgcn_mfma_f32_16x16x32_bf16(pf0, v0, oacc[dc], 0, 0, 0);
    oacc[dc] = __builtin_amdgcn_mfma_f32_16x16x32_bf16(pf1, v1, oacc[dc], 0, 0, 0);
  }

#pragma unroll
  for (int r = 0; r < 4; ++r) {
    const int row = nrow0 + r;
    if (row < 49) {
#pragma unroll
      for (int dc = 0; dc < 4; ++dc)
        Ps[row][16 * dc + lr] = f2bf(oacc[dc][r] * rs[r]);
    }
  }
  asm volatile("s_waitcnt lgkmcnt(0)" ::: "memory");
  __builtin_amdgcn_sched_barrier(0);

  {
    const int r0 = 16 * w;
    const int r1 = (16 * w + 16 < 49) ? 16 * w + 16 : 49;
    u16* ob = attn_out + (long)(b * 49) * 768 + h * 64;
    for (int it = l; it < (r1 - r0) * 8; it += 64) {
      const int row = r0 + (it >> 3), cc = (it & 7) << 3;
      *(ulonglong2*)&ob[(long)row * 768 + cc] = *(const ulonglong2*)&Ps[row][cc];
    }
    float* pout = prev_out + (long)bh * 2401;
    for (int i = r0 * 49 + l; i < r1 * 49; i += 64) pout[i] = bf2f(SB[i]);
  }
}

// ---------------- launch ----------------
extern "C" void kernel_launch(void* const* d_in, const int* in_sizes, int n_in,
                              void* d_out, int out_size, void* d_ws, size_t ws_size,
                              hipStream_t stream) {
  const float* x = (const float*)d_in[0];
  const float* prev = (const float*)d_in[1];
  const float* qkv_w = (const float*)d_in[2];
  const float* proj_w = (const float*)d_in[3];
  const float* proj_b = (const float*)d_in[4];
  const float* bias_table = (const float*)d_in[5];
  const int* rel_idx = (const int*)d_in[6];

  const int B = in_sizes[0] / (49 * 768);  // 1024
  const int M = B * 49;                    // 50176 = 196*256 = 392*128

  float* out0 = (float*)d_out;             // [M,768]
  float* out1 = out0 + (size_t)M * 768;    // [B,12,49,49]

  char* ws = (char*)d_ws;
  u16* xbf = (u16*)ws;                                     // M*768 bf16 (reused as attn_out)
  u16* qkvbf = (u16*)(ws + (size_t)M * 768 * 2);           // M*2304 bf16
  u16* qkvwT = (u16*)(ws + (size_t)M * 768 * 2 + (size_t)M * 2304 * 2);  // [2304,768]
  u16* projwT = qkvwT + 2304 * 768;                        // [768,768]
  float* biasM = (float*)(projwT + 768 * 768);             // [12,2401]

  prep<<<2048 + 1728 + 576 + 113, 256, 0, stream>>>(
      x, xbf, M * 768 / 4, qkv_w, qkvwT, proj_w, projwT,
      bias_table, rel_idx, biasM);

  gemm256<true><<<(M / 256) * (2304 / 256), 512, 0, stream>>>(
      xbf, qkvwT, qkvbf, nullptr, M, 2304, 768, 2304 / 256);

  attn_kernel<<<B * 12, 256, 0, stream>>>(qkvbf, prev, biasM, out1, xbf);

  gemm128<false><<<(M / 128) * (768 / 128), 256, 0, stream>>>(
      xbf, projwT, out0, proj_b, M, 768, 768, 768 / 128);
}

// Round 16
// 462.221 us; speedup vs baseline: 1.0001x; 1.0001x over previous
//
#include <hip/hip_runtime.h>

typedef unsigned short u16;
typedef unsigned int u32;
typedef float f32x4 __attribute__((ext_vector_type(4)));
typedef __bf16 bf16x8 __attribute__((ext_vector_type(8)));

#define DEV static __device__ __forceinline__

DEV u16 f2bf(float f) {
  u32 u = __builtin_bit_cast(u32, f);
  u += 0x7fffu + ((u >> 16) & 1u);
  return (u16)(u >> 16);
}

DEV float bf2f(u16 v) {
  u32 u = ((u32)v) << 16;
  return __builtin_bit_cast(float, u);
}

DEV void gload_lds16(const void* g, void* l) {
  __builtin_amdgcn_global_load_lds(
      (const __attribute__((address_space(1))) u32*)g,
      (__attribute__((address_space(3))) u32*)l, 16, 0, 0);
}

// ---------------- fused preprocessing: cvt + 2 transposes + bias gather ----
__global__ __launch_bounds__(256) void prep(
    const float* __restrict__ x, u16* __restrict__ xbf, int n4,
    const float* __restrict__ qkv_w, u16* __restrict__ qkvwT,
    const float* __restrict__ proj_w, u16* __restrict__ projwT,
    const float* __restrict__ bias_table, const int* __restrict__ rel_idx,
    float* __restrict__ biasM) {
  __shared__ float tile[32][33];
  const int bid = blockIdx.x;
  if (bid < 2048) {
    int i = bid * 256 + threadIdx.x;
    for (; i < n4; i += 2048 * 256) {
      const float4 v = ((const float4*)x)[i];
      ushort4 o;
      o.x = f2bf(v.x); o.y = f2bf(v.y); o.z = f2bf(v.z); o.w = f2bf(v.w);
      ((ushort4*)xbf)[i] = o;
    }
  } else if (bid < 2048 + 1728 + 576) {
    const bool qk = bid < 2048 + 1728;
    const int b2 = qk ? bid - 2048 : bid - (2048 + 1728);
    const float* in = qk ? qkv_w : proj_w;
    u16* out = qk ? qkvwT : projwT;
    const int N = qk ? 2304 : 768;
    const int nbx = N >> 5;
    const int bx = b2 % nbx, by = b2 / nbx;
    const int tx = threadIdx.x & 31, ty = threadIdx.x >> 5;
#pragma unroll
    for (int j = 0; j < 4; ++j)
      tile[ty + 8 * j][tx] = in[(long)(by * 32 + ty + 8 * j) * N + bx * 32 + tx];
    __syncthreads();
#pragma unroll
    for (int j = 0; j < 4; ++j)
      out[(long)(bx * 32 + ty + 8 * j) * 768 + by * 32 + tx] = f2bf(tile[tx][ty + 8 * j]);
  } else {
    const int i = (bid - (2048 + 1728 + 576)) * 256 + threadIdx.x;
    if (i < 12 * 2401) {
      const int h = i / 2401, p = i - h * 2401;
      biasM[i] = bias_table[rel_idx[p] * 12 + h];
    }
  }
}

// ---------------- 256x256 deep-pipelined GEMM (best measured: r6/r10) ------
template <bool OUT_BF16>
__global__ __launch_bounds__(512, 2) void gemm256(
    const u16* __restrict__ A, const u16* __restrict__ BT,
    void* __restrict__ C, const float* __restrict__ bias,
    int M, int N, int K, int nbn) {
  __shared__ alignas(16) char lds[131072];
  const int t = threadIdx.x;
  const int w = t >> 6, l = t & 63, lr = l & 15, lhi = l >> 4;
  const int wr = w >> 2, wc = w & 3;

  const int nwg = gridDim.x;
  const int q = nwg >> 3, r = nwg & 7;
  const int xcd = blockIdx.x & 7, lid = blockIdx.x >> 3;
  const int swz = (xcd < r ? xcd * (q + 1) : r * (q + 1) + (xcd - r) * q) + lid;
  const int bm = swz / nbn, bn = swz % nbn;

  const int T = K >> 5;
  const long Kb = (long)K * 2;

  const int unswz = (l & 7) ^ (l >> 3);
  const int arow = 2 * (l >> 3) + (unswz >> 2);
  const int acolb = (unswz & 3) << 4;
  const char* gA0 = (const char*)A + (long)(bm * 256 + w * 32 + arow) * Kb + acolb;
  const char* gA1 = gA0 + 16 * Kb;
  const char* gB0 = (const char*)BT + (long)(bn * 256 + w * 32 + arow) * Kb + acolb;
  const char* gB1 = gB0 + 16 * Kb;
  const int ldA0 = w * 2048, ldA1 = w * 2048 + 1024;
  const int ldB0 = 16384 + w * 2048, ldB1 = 16384 + w * 2048 + 1024;

#define STAGE(tt)                               \
  {                                             \
    const int bb = ((tt) & 3) * 32768;          \
    const long ko = (long)(tt) * 64;            \
    gload_lds16(gA0 + ko, lds + bb + ldA0);     \
    gload_lds16(gA1 + ko, lds + bb + ldA1);     \
    gload_lds16(gB0 + ko, lds + bb + ldB0);     \
    gload_lds16(gB1 + ko, lds + bb + ldB1);     \
  }
#define BAR                                  \
  asm volatile("" ::: "memory");             \
  __builtin_amdgcn_s_barrier();              \
  asm volatile("" ::: "memory")

  const int rblk = ((((lr & 1) << 2) | lhi) ^ (lr >> 1));
  const int aoff0 = (wr * 64 + (lr >> 1)) * 128 + rblk * 16;
  const int boff0 = 16384 + (wc * 32 + (lr >> 1)) * 128 + rblk * 16;

  f32x4 acc[8][4];
#pragma unroll
  for (int m = 0; m < 8; ++m)
#pragma unroll
    for (int n = 0; n < 4; ++n) acc[m][n] = (f32x4){0.f, 0.f, 0.f, 0.f};
  bf16x8 afrX[4], bfrX[4], afrY[4], bfrY[4];

#define CLUSTER1(S)                                                        \
  __builtin_amdgcn_s_setprio(1);                                           \
  _Pragma("unroll") for (int m = 0; m < 4; ++m)                            \
      _Pragma("unroll") for (int n = 0; n < 4; ++n)                        \
          acc[m][n] = __builtin_amdgcn_mfma_f32_16x16x32_bf16(             \
              afr##S[m], bfr##S[n], acc[m][n], 0, 0, 0);                   \
  __builtin_amdgcn_s_setprio(0)
#define CLUSTER2(S)                                                        \
  __builtin_amdgcn_s_setprio(1);                                           \
  _Pragma("unroll") for (int m = 0; m < 4; ++m)                            \
      _Pragma("unroll") for (int n = 0; n < 4; ++n)                        \
          acc[m + 4][n] = __builtin_amdgcn_mfma_f32_16x16x32_bf16(         \
              afr2[m], bfr##S[n], acc[m + 4][n], 0, 0, 0);                 \
  __builtin_amdgcn_s_setprio(0)

#define BODY(kt, S, R)                                                     \
  {                                                                        \
    if ((kt) + 3 < T) STAGE((kt) + 3);                                     \
    const int bbc = ((kt) & 3) * 32768;                                    \
    const int nx = ((kt) + 1 < T) ? (kt) + 1 : (kt);                       \
    const int bbn = (nx & 3) * 32768;                                      \
    bf16x8 afr2[4];                                                        \
    _Pragma("unroll") for (int m = 0; m < 4; ++m)                          \
        afr2[m] = *(const bf16x8*)(lds + bbc + aoff0 + (m + 4) * 1024);    \
    CLUSTER1(S);                                                           \
    _Pragma("unroll") for (int n = 0; n < 4; ++n)                          \
        bfr##R[n] = *(const bf16x8*)(lds + bbn + boff0 + n * 1024);        \
    CLUSTER2(S);                                                           \
    _Pragma("unroll") for (int m = 0; m < 4; ++m)                          \
        afr##R[m] = *(const bf16x8*)(lds + bbn + aoff0 + m * 1024);        \
    if ((kt) + 3 < T) {                                                    \
      asm volatile("s_waitcnt vmcnt(4)" ::: "memory");                     \
    } else {                                                               \
      asm volatile("s_waitcnt vmcnt(0)" ::: "memory");                     \
    }                                                                      \
    BAR;                                                                   \
  }

  STAGE(0); STAGE(1); STAGE(2);
  asm volatile("s_waitcnt vmcnt(4)" ::: "memory");
  BAR;
#pragma unroll
  for (int n = 0; n < 4; ++n) bfrX[n] = *(const bf16x8*)(lds + boff0 + n * 1024);
#pragma unroll
  for (int m = 0; m < 4; ++m) afrX[m] = *(const bf16x8*)(lds + aoff0 + m * 1024);

  for (int i = 0; i < T / 2; ++i) {
    BODY(2 * i, X, Y);
    BODY(2 * i + 1, Y, X);
  }
#undef STAGE
#undef BODY

  const int row0 = bm * 256 + wr * 128 + 4 * lhi;
  const int col0 = bn * 256 + wc * 64 + lr;
  if (OUT_BF16) {
    u16* Cc = (u16*)C;
#pragma unroll
    for (int m = 0; m < 8; ++m)
#pragma unroll
      for (int rr = 0; rr < 4; ++rr) {
        const long row = row0 + m * 16 + rr;
#pragma unroll
        for (int n = 0; n < 4; ++n)
          Cc[row * N + col0 + n * 16] = f2bf(acc[m][n][rr]);
      }
  } else {
    float* Cf = (float*)C;
    float bv[4];
#pragma unroll
    for (int n = 0; n < 4; ++n) bv[n] = bias[col0 + n * 16];
#pragma unroll
    for (int m = 0; m < 8; ++m)
#pragma unroll
      for (int rr = 0; rr < 4; ++rr) {
        const long row = row0 + m * 16 + rr;
#pragma unroll
        for (int n = 0; n < 4; ++n)
          Cf[row * N + col0 + n * 16] = acc[m][n][rr] + bv[n];
      }
  }
#undef BAR
#undef CLUSTER1
#undef CLUSTER2
}

// ---------------- fused attention (v5: ONE block barrier) ------------------
// one block (256 thr, 4 waves) per (b,h). N=49 padded to 64, hd=64.
// SB rows are wave-local (softmax reads only rows 16w..16w+15, clamp 48 ->
// wave 3), so each wave loads + fills ITS OWN SB range; the fill->read dep
// is same-wave (lgkmcnt(0)+sched_barrier, rule #18). Only barrier #1
// (cross-wave Q/K/VT staging) remains. T14 in-flight prev/bias preserved.
__global__ __launch_bounds__(256) void attn_kernel(
    const u16* __restrict__ qkv,        // [B*49, 2304] bf16
    const float* __restrict__ prev,     // [B,12,49,49]
    const float* __restrict__ biasM,    // [12,49*49]
    float* __restrict__ prev_out,       // [B,12,49,49]
    u16* __restrict__ attn_out) {       // [B*49, 768] bf16
  __shared__ u16 Qs[64][72];   // Q -> P -> O (all wave-local transitions)
  __shared__ u16 Ks[64][72];
  __shared__ u16 VTs[64][72];
  __shared__ u16 SB[2432];     // prev+bias then scores, bf16

  const int bh = blockIdx.x;
  const int b = bh / 12, h = bh % 12;
  const int t = threadIdx.x, w = t >> 6, l = t & 63, lr = l & 15, lhi = l >> 4;

  // ---- stage Q,K,V^T into LDS (cross-wave) ----
  const u16* base = qkv + (long)(b * 49) * 2304 + h * 64;
  for (int idx = t; idx < 49 * 16; idx += 256) {
    const int n = idx >> 4, c4 = (idx & 15) << 2;
    const u16* rp = base + (long)n * 2304;
    ushort4 qv = *(const ushort4*)(rp + c4);
    ushort4 kv = *(const ushort4*)(rp + 768 + c4);
    ushort4 vv = *(const ushort4*)(rp + 1536 + c4);
    *(ushort4*)&Qs[n][c4] = qv;
    *(ushort4*)&Ks[n][c4] = kv;
    VTs[c4 + 0][n] = vv.x;
    VTs[c4 + 1][n] = vv.y;
    VTs[c4 + 2][n] = vv.z;
    VTs[c4 + 3][n] = vv.w;
  }
  for (int idx = t; idx < 1024; idx += 256) {
    const int j = idx & 15;
    if (j) VTs[idx >> 4][48 + j] = 0;
  }

  // ---- issue WAVE-LOCAL prev/bias to registers (in flight across QK^T) ----
  const int r0 = 16 * w;
  const int i0 = r0 * 49;
  const int i1 = (w == 3) ? 2401 : i0 + 784;  // wave 3 owns only row 48
  float prevR[13], biasR[13];
  {
    const float* pv = prev + (long)bh * 2401;
    const float* bm = biasM + h * 2401;
#pragma unroll
    for (int k = 0; k < 13; ++k) {
      const int i = i0 + l + 64 * k;
      if (i < i1) {
        prevR[k] = pv[i];
        biasR[k] = bm[i];
      }
    }
  }

  // barrier #1 (the only one): drain LDS writes; vmcnt stays outstanding
  asm volatile("s_waitcnt lgkmcnt(0)" ::: "memory");
  __builtin_amdgcn_s_barrier();
  asm volatile("" ::: "memory");

  // ---- QK^T ----
  bf16x8 af0 = *(const bf16x8*)&Qs[16 * w + lr][lhi * 8];
  bf16x8 af1 = *(const bf16x8*)&Qs[16 * w + lr][32 + lhi * 8];
  f32x4 sacc[4];
#pragma unroll
  for (int tc = 0; tc < 4; ++tc) {
    sacc[tc] = (f32x4){0.f, 0.f, 0.f, 0.f};
    bf16x8 b0 = *(const bf16x8*)&Ks[16 * tc + lr][lhi * 8];
    bf16x8 b1 = *(const bf16x8*)&Ks[16 * tc + lr][32 + lhi * 8];
    sacc[tc] = __builtin_amdgcn_mfma_f32_16x16x32_bf16(af0, b0, sacc[tc], 0, 0, 0);
    sacc[tc] = __builtin_amdgcn_mfma_f32_16x16x32_bf16(af1, b1, sacc[tc], 0, 0, 0);
  }

  // ---- land own prev/bias, fill own SB rows (same-wave dep only) ----
  asm volatile("s_waitcnt vmcnt(0)" ::: "memory");
#pragma unroll
  for (int k = 0; k < 13; ++k) {
    const int i = i0 + l + 64 * k;
    if (i < i1) SB[i] = f2bf(prevR[k] + biasR[k]);
  }
  asm volatile("s_waitcnt lgkmcnt(0)" ::: "memory");
  __builtin_amdgcn_sched_barrier(0);

  // ---- epilogue + softmax (SB + Ps: all wave-local rows) ----
  u16 (*Ps)[72] = Qs;
  const int nrow0 = 16 * w + 4 * lhi;
  float rs[4];
#pragma unroll
  for (int r = 0; r < 4; ++r) {
    const int row = nrow0 + r;
    const bool rv = row < 49;
    float sv[4];
#pragma unroll
    for (int tc = 0; tc < 4; ++tc) {
      const int col = 16 * tc + lr;
      const bool valid = rv && (col < 49);
      const int sidx = (row < 49 ? row : 48) * 49 + (col < 49 ? col : 48);
      const float pb = bf2f(SB[sidx]);
      const float s = sacc[tc][r] * 0.125f + pb;
      if (valid) SB[sidx] = f2bf(s);
      sv[tc] = valid ? s : -INFINITY;
    }
    float mx = fmaxf(fmaxf(sv[0], sv[1]), fmaxf(sv[2], sv[3]));
#pragma unroll
    for (int off = 8; off; off >>= 1) mx = fmaxf(mx, __shfl_xor(mx, off, 16));
    float e[4], sum = 0.f;
#pragma unroll
    for (int tc = 0; tc < 4; ++tc) {
      e[tc] = __expf(sv[tc] - mx);
      sum += e[tc];
    }
#pragma unroll
    for (int off = 8; off; off >>= 1) sum += __shfl_xor(sum, off, 16);
    rs[r] = 1.0f / sum;
#pragma unroll
    for (int tc = 0; tc < 4; ++tc)
      Ps[row][16 * tc + lr] = rv ? f2bf(e[tc]) : (u16)0;
  }

  asm volatile("s_waitcnt lgkmcnt(0)" ::: "memory");
  __builtin_amdgcn_sched_barrier(0);

  // ---- P*V (pf from own Ps rows; VTs published at barrier #1) ----
  bf16x8 pf0 = *(const bf16x8*)&Ps[16 * w + lr][lhi * 8];
  bf16x8 pf1 = *(const bf16x8*)&Ps[16 * w + lr][32 + lhi * 8];
  f32x4 oacc[4];
#pragma unroll
  for (int dc = 0; dc < 4; ++dc) {
    oacc[dc] = (f32x4){0.f, 0.f, 0.f, 0.f};
    bf16x8 v0 = *(const bf16x8*)&VTs[16 * dc + lr][lhi * 8];
    bf16x8 v1 = *(const bf16x8*)&VTs[16 * dc + lr][32 + lhi * 8];
    oacc[dc] = __builtin_amdgcn_mfma_f32_16x16x32_bf16(pf0, v0, oacc[dc], 0, 0, 0);
    oacc[dc] = __builtin_amdgcn_mfma_f32_16x16x32_bf16(pf1, v1, oacc[dc], 0, 0, 0);
  }

  // ---- repack O into own Ps rows ----
#pragma unroll
  for (int r = 0; r < 4; ++r) {
    const int row = nrow0 + r;
    if (row < 49) {
#pragma unroll
      for (int dc = 0; dc < 4; ++dc)
        Ps[row][16 * dc + lr] = f2bf(oacc[dc][r] * rs[r]);
    }
  }
  asm volatile("s_waitcnt lgkmcnt(0)" ::: "memory");
  __builtin_amdgcn_sched_barrier(0);

  // ---- per-wave streaming: wave w owns rows [16w, min(16w+16,49)) ----
  {
    const int r1 = (16 * w + 16 < 49) ? 16 * w + 16 : 49;
    u16* ob = attn_out + (long)(b * 49) * 768 + h * 64;
    for (int it = l; it < (r1 - r0) * 8; it += 64) {
      const int row = r0 + (it >> 3), cc = (it & 7) << 3;
      *(ulonglong2*)&ob[(long)row * 768 + cc] = *(const ulonglong2*)&Ps[row][cc];
    }
    float* pout = prev_out + (long)bh * 2401;
    for (int i = i0 + l; i < r1 * 49; i += 64) pout[i] = bf2f(SB[i]);
  }
}

// ---------------- launch ----------------
extern "C" void kernel_launch(void* const* d_in, const int* in_sizes, int n_in,
                              void* d_out, int out_size, void* d_ws, size_t ws_size,
                              hipStream_t stream) {
  const float* x = (const float*)d_in[0];
  const float* prev = (const float*)d_in[1];
  const float* qkv_w = (const float*)d_in[2];
  const float* proj_w = (const float*)d_in[3];
  const float* proj_b = (const float*)d_in[4];
  const float* bias_table = (const float*)d_in[5];
  const int* rel_idx = (const int*)d_in[6];

  const int B = in_sizes[0] / (49 * 768);  // 1024
  const int M = B * 49;                    // 50176 = 196*256

  float* out0 = (float*)d_out;             // [M,768]
  float* out1 = out0 + (size_t)M * 768;    // [B,12,49,49]

  char* ws = (char*)d_ws;
  u16* xbf = (u16*)ws;                                     // M*768 bf16 (reused as attn_out)
  u16* qkvbf = (u16*)(ws + (size_t)M * 768 * 2);           // M*2304 bf16
  u16* qkvwT = (u16*)(ws + (size_t)M * 768 * 2 + (size_t)M * 2304 * 2);  // [2304,768]
  u16* projwT = qkvwT + 2304 * 768;                        // [768,768]
  float* biasM = (float*)(projwT + 768 * 768);             // [12,2401]

  prep<<<2048 + 1728 + 576 + 113, 256, 0, stream>>>(
      x, xbf, M * 768 / 4, qkv_w, qkvwT, proj_w, projwT,
      bias_table, rel_idx, biasM);

  gemm256<true><<<(M / 256) * (2304 / 256), 512, 0, stream>>>(
      xbf, qkvwT, qkvbf, nullptr, M, 2304, 768, 2304 / 256);

  attn_kernel<<<B * 12, 256, 0, stream>>>(qkvbf, prev, biasM, out1, xbf);

  gemm256<false><<<(M / 256) * (768 / 256), 512, 0, stream>>>(
      xbf, projwT, out0, proj_b, M, 768, 768, 768 / 256);
}

// Round 17
// 454.964 us; speedup vs baseline: 1.0161x; 1.0160x over previous
//
#include <hip/hip_runtime.h>

typedef unsigned short u16;
typedef unsigned int u32;
typedef float f32x4 __attribute__((ext_vector_type(4)));
typedef __bf16 bf16x8 __attribute__((ext_vector_type(8)));

#define DEV static __device__ __forceinline__

DEV u16 f2bf(float f) {
  u32 u = __builtin_bit_cast(u32, f);
  u += 0x7fffu + ((u >> 16) & 1u);
  return (u16)(u >> 16);
}

DEV float bf2f(u16 v) {
  u32 u = ((u32)v) << 16;
  return __builtin_bit_cast(float, u);
}

DEV void gload_lds16(const void* g, void* l) {
  __builtin_amdgcn_global_load_lds(
      (const __attribute__((address_space(1))) u32*)g,
      (__attribute__((address_space(3))) u32*)l, 16, 0, 0);
}

// ---------------- fused preprocessing: cvt + 2 transposes + bias gather ----
__global__ __launch_bounds__(256) void prep(
    const float* __restrict__ x, u16* __restrict__ xbf, int n4,
    const float* __restrict__ qkv_w, u16* __restrict__ qkvwT,
    const float* __restrict__ proj_w, u16* __restrict__ projwT,
    const float* __restrict__ bias_table, const int* __restrict__ rel_idx,
    float* __restrict__ biasM) {
  __shared__ float tile[32][33];
  const int bid = blockIdx.x;
  if (bid < 2048) {
    int i = bid * 256 + threadIdx.x;
    for (; i < n4; i += 2048 * 256) {
      const float4 v = ((const float4*)x)[i];
      ushort4 o;
      o.x = f2bf(v.x); o.y = f2bf(v.y); o.z = f2bf(v.z); o.w = f2bf(v.w);
      ((ushort4*)xbf)[i] = o;
    }
  } else if (bid < 2048 + 1728 + 576) {
    const bool qk = bid < 2048 + 1728;
    const int b2 = qk ? bid - 2048 : bid - (2048 + 1728);
    const float* in = qk ? qkv_w : proj_w;
    u16* out = qk ? qkvwT : projwT;
    const int N = qk ? 2304 : 768;
    const int nbx = N >> 5;
    const int bx = b2 % nbx, by = b2 / nbx;
    const int tx = threadIdx.x & 31, ty = threadIdx.x >> 5;
#pragma unroll
    for (int j = 0; j < 4; ++j)
      tile[ty + 8 * j][tx] = in[(long)(by * 32 + ty + 8 * j) * N + bx * 32 + tx];
    __syncthreads();
#pragma unroll
    for (int j = 0; j < 4; ++j)
      out[(long)(bx * 32 + ty + 8 * j) * 768 + by * 32 + tx] = f2bf(tile[tx][ty + 8 * j]);
  } else {
    const int i = (bid - (2048 + 1728 + 576)) * 256 + threadIdx.x;
    if (i < 12 * 2401) {
      const int h = i / 2401, p = i - h * 2401;
      biasM[i] = bias_table[rel_idx[p] * 12 + h];
    }
  }
}

// ---------------- 256x256 deep-pipelined GEMM (best measured: r6/r10) ------
// LDS layout (per 32KB buffer): A = 128 lines x 128B (2 m-rows/line), B @+16384.
// Swizzle: (row, 16B-blk b) -> line = row>>1, slot = (row&1)*4+b, slot ^= line&7.
// Conflict-free (measured 0). Depth-3 staging, vmcnt(4) at bottom so tiles
// kt+1,kt+2 are published entering iter kt+1 -> next tile's fragments
// prefetched in-register DURING iter kt (ping-pong X/Y).
template <bool OUT_BF16>
__global__ __launch_bounds__(512, 2) void gemm256(
    const u16* __restrict__ A, const u16* __restrict__ BT,
    void* __restrict__ C, const float* __restrict__ bias,
    int M, int N, int K, int nbn) {
  __shared__ alignas(16) char lds[131072];
  const int t = threadIdx.x;
  const int w = t >> 6, l = t & 63, lr = l & 15, lhi = l >> 4;
  const int wr = w >> 2, wc = w & 3;

  const int nwg = gridDim.x;
  const int q = nwg >> 3, r = nwg & 7;
  const int xcd = blockIdx.x & 7, lid = blockIdx.x >> 3;
  const int swz = (xcd < r ? xcd * (q + 1) : r * (q + 1) + (xcd - r) * q) + lid;
  const int bm = swz / nbn, bn = swz % nbn;

  const int T = K >> 5;
  const long Kb = (long)K * 2;

  const int unswz = (l & 7) ^ (l >> 3);
  const int arow = 2 * (l >> 3) + (unswz >> 2);
  const int acolb = (unswz & 3) << 4;
  const char* gA0 = (const char*)A + (long)(bm * 256 + w * 32 + arow) * Kb + acolb;
  const char* gA1 = gA0 + 16 * Kb;
  const char* gB0 = (const char*)BT + (long)(bn * 256 + w * 32 + arow) * Kb + acolb;
  const char* gB1 = gB0 + 16 * Kb;
  const int ldA0 = w * 2048, ldA1 = w * 2048 + 1024;
  const int ldB0 = 16384 + w * 2048, ldB1 = 16384 + w * 2048 + 1024;

#define STAGE(tt)                               \
  {                                             \
    const int bb = ((tt) & 3) * 32768;          \
    const long ko = (long)(tt) * 64;            \
    gload_lds16(gA0 + ko, lds + bb + ldA0);     \
    gload_lds16(gA1 + ko, lds + bb + ldA1);     \
    gload_lds16(gB0 + ko, lds + bb + ldB0);     \
    gload_lds16(gB1 + ko, lds + bb + ldB1);     \
  }
#define BAR                                  \
  asm volatile("" ::: "memory");             \
  __builtin_amdgcn_s_barrier();              \
  asm volatile("" ::: "memory")

  const int rblk = ((((lr & 1) << 2) | lhi) ^ (lr >> 1));
  const int aoff0 = (wr * 64 + (lr >> 1)) * 128 + rblk * 16;
  const int boff0 = 16384 + (wc * 32 + (lr >> 1)) * 128 + rblk * 16;

  f32x4 acc[8][4];
#pragma unroll
  for (int m = 0; m < 8; ++m)
#pragma unroll
    for (int n = 0; n < 4; ++n) acc[m][n] = (f32x4){0.f, 0.f, 0.f, 0.f};
  bf16x8 afrX[4], bfrX[4], afrY[4], bfrY[4];

#define CLUSTER1(S)                                                        \
  __builtin_amdgcn_s_setprio(1);                                           \
  _Pragma("unroll") for (int m = 0; m < 4; ++m)                            \
      _Pragma("unroll") for (int n = 0; n < 4; ++n)                        \
          acc[m][n] = __builtin_amdgcn_mfma_f32_16x16x32_bf16(             \
              afr##S[m], bfr##S[n], acc[m][n], 0, 0, 0);                   \
  __builtin_amdgcn_s_setprio(0)
#define CLUSTER2(S)                                                        \
  __builtin_amdgcn_s_setprio(1);                                           \
  _Pragma("unroll") for (int m = 0; m < 4; ++m)                            \
      _Pragma("unroll") for (int n = 0; n < 4; ++n)                        \
          acc[m + 4][n] = __builtin_amdgcn_mfma_f32_16x16x32_bf16(         \
              afr2[m], bfr##S[n], acc[m + 4][n], 0, 0, 0);                 \
  __builtin_amdgcn_s_setprio(0)

#define BODY(kt, S, R)                                                     \
  {                                                                        \
    if ((kt) + 3 < T) STAGE((kt) + 3);                                     \
    const int bbc = ((kt) & 3) * 32768;                                    \
    const int nx = ((kt) + 1 < T) ? (kt) + 1 : (kt);                       \
    const int bbn = (nx & 3) * 32768;                                      \
    bf16x8 afr2[4];                                                        \
    _Pragma("unroll") for (int m = 0; m < 4; ++m)                          \
        afr2[m] = *(const bf16x8*)(lds + bbc + aoff0 + (m + 4) * 1024);    \
    CLUSTER1(S);                                                           \
    _Pragma("unroll") for (int n = 0; n < 4; ++n)                          \
        bfr##R[n] = *(const bf16x8*)(lds + bbn + boff0 + n * 1024);        \
    CLUSTER2(S);                                                           \
    _Pragma("unroll") for (int m = 0; m < 4; ++m)                          \
        afr##R[m] = *(const bf16x8*)(lds + bbn + aoff0 + m * 1024);        \
    if ((kt) + 3 < T) {                                                    \
      asm volatile("s_waitcnt vmcnt(4)" ::: "memory");                     \
    } else {                                                               \
      asm volatile("s_waitcnt vmcnt(0)" ::: "memory");                     \
    }                                                                      \
    BAR;                                                                   \
  }

  STAGE(0); STAGE(1); STAGE(2);
  asm volatile("s_waitcnt vmcnt(4)" ::: "memory");
  BAR;
#pragma unroll
  for (int n = 0; n < 4; ++n) bfrX[n] = *(const bf16x8*)(lds + boff0 + n * 1024);
#pragma unroll
  for (int m = 0; m < 4; ++m) afrX[m] = *(const bf16x8*)(lds + aoff0 + m * 1024);

  for (int i = 0; i < T / 2; ++i) {
    BODY(2 * i, X, Y);
    BODY(2 * i + 1, Y, X);
  }
#undef STAGE
#undef BODY

  const int row0 = bm * 256 + wr * 128 + 4 * lhi;
  const int col0 = bn * 256 + wc * 64 + lr;
  if (OUT_BF16) {
    u16* Cc = (u16*)C;
#pragma unroll
    for (int m = 0; m < 8; ++m)
#pragma unroll
      for (int rr = 0; rr < 4; ++rr) {
        const long row = row0 + m * 16 + rr;
#pragma unroll
        for (int n = 0; n < 4; ++n)
          Cc[row * N + col0 + n * 16] = f2bf(acc[m][n][rr]);
      }
  } else {
    float* Cf = (float*)C;
    float bv[4];
#pragma unroll
    for (int n = 0; n < 4; ++n) bv[n] = bias[col0 + n * 16];
#pragma unroll
    for (int m = 0; m < 8; ++m)
#pragma unroll
      for (int rr = 0; rr < 4; ++rr) {
        const long row = row0 + m * 16 + rr;
#pragma unroll
        for (int n = 0; n < 4; ++n)
          Cf[row * N + col0 + n * 16] = acc[m][n][rr] + bv[n];
      }
  }
#undef BAR
#undef CLUSTER1
#undef CLUSTER2
}

// ---------------- fused attention (r14 best: 2 barriers, wave-local tail) --
__global__ __launch_bounds__(256) void attn_kernel(
    const u16* __restrict__ qkv,        // [B*49, 2304] bf16
    const float* __restrict__ prev,     // [B,12,49,49]
    const float* __restrict__ biasM,    // [12,49*49]
    float* __restrict__ prev_out,       // [B,12,49,49]
    u16* __restrict__ attn_out) {       // [B*49, 768] bf16
  __shared__ u16 Qs[64][72];   // Q -> P -> O (all wave-local transitions)
  __shared__ u16 Ks[64][72];
  __shared__ u16 VTs[64][72];
  __shared__ u16 SB[2432];     // prev+bias then scores, bf16

  const int bh = blockIdx.x;
  const int b = bh / 12, h = bh % 12;
  const int t = threadIdx.x, w = t >> 6, l = t & 63, lr = l & 15, lhi = l >> 4;

  const u16* base = qkv + (long)(b * 49) * 2304 + h * 64;
  for (int idx = t; idx < 49 * 16; idx += 256) {
    const int n = idx >> 4, c4 = (idx & 15) << 2;
    const u16* rp = base + (long)n * 2304;
    ushort4 qv = *(const ushort4*)(rp + c4);
    ushort4 kv = *(const ushort4*)(rp + 768 + c4);
    ushort4 vv = *(const ushort4*)(rp + 1536 + c4);
    *(ushort4*)&Qs[n][c4] = qv;
    *(ushort4*)&Ks[n][c4] = kv;
    VTs[c4 + 0][n] = vv.x;
    VTs[c4 + 1][n] = vv.y;
    VTs[c4 + 2][n] = vv.z;
    VTs[c4 + 3][n] = vv.w;
  }
  for (int idx = t; idx < 1024; idx += 256) {
    const int j = idx & 15;
    if (j) VTs[idx >> 4][48 + j] = 0;
  }

  float prevR[10], biasR[10];
  {
    const float* pv = prev + (long)bh * 2401;
    const float* bm = biasM + h * 2401;
#pragma unroll
    for (int k = 0; k < 10; ++k) {
      const int i = t + 256 * k;
      if (i < 2401) {
        prevR[k] = pv[i];
        biasR[k] = bm[i];
      }
    }
  }

  asm volatile("s_waitcnt lgkmcnt(0)" ::: "memory");
  __builtin_amdgcn_s_barrier();
  asm volatile("" ::: "memory");

  bf16x8 af0 = *(const bf16x8*)&Qs[16 * w + lr][lhi * 8];
  bf16x8 af1 = *(const bf16x8*)&Qs[16 * w + lr][32 + lhi * 8];
  f32x4 sacc[4];
#pragma unroll
  for (int tc = 0; tc < 4; ++tc) {
    sacc[tc] = (f32x4){0.f, 0.f, 0.f, 0.f};
    bf16x8 b0 = *(const bf16x8*)&Ks[16 * tc + lr][lhi * 8];
    bf16x8 b1 = *(const bf16x8*)&Ks[16 * tc + lr][32 + lhi * 8];
    sacc[tc] = __builtin_amdgcn_mfma_f32_16x16x32_bf16(af0, b0, sacc[tc], 0, 0, 0);
    sacc[tc] = __builtin_amdgcn_mfma_f32_16x16x32_bf16(af1, b1, sacc[tc], 0, 0, 0);
  }

  asm volatile("s_waitcnt vmcnt(0)" ::: "memory");
#pragma unroll
  for (int k = 0; k < 10; ++k) {
    const int i = t + 256 * k;
    if (i < 2401) SB[i] = f2bf(prevR[k] + biasR[k]);
  }
  asm volatile("s_waitcnt lgkmcnt(0)" ::: "memory");
  __builtin_amdgcn_s_barrier();
  asm volatile("" ::: "memory");

  u16 (*Ps)[72] = Qs;
  const int nrow0 = 16 * w + 4 * lhi;
  float rs[4];
#pragma unroll
  for (int r = 0; r < 4; ++r) {
    const int row = nrow0 + r;
    const bool rv = row < 49;
    float sv[4];
#pragma unroll
    for (int tc = 0; tc < 4; ++tc) {
      const int col = 16 * tc + lr;
      const bool valid = rv && (col < 49);
      const int sidx = (row < 49 ? row : 48) * 49 + (col < 49 ? col : 48);
      const float pb = bf2f(SB[sidx]);
      const float s = sacc[tc][r] * 0.125f + pb;
      if (valid) SB[sidx] = f2bf(s);
      sv[tc] = valid ? s : -INFINITY;
    }
    float mx = fmaxf(fmaxf(sv[0], sv[1]), fmaxf(sv[2], sv[3]));
#pragma unroll
    for (int off = 8; off; off >>= 1) mx = fmaxf(mx, __shfl_xor(mx, off, 16));
    float e[4], sum = 0.f;
#pragma unroll
    for (int tc = 0; tc < 4; ++tc) {
      e[tc] = __expf(sv[tc] - mx);
      sum += e[tc];
    }
#pragma unroll
    for (int off = 8; off; off >>= 1) sum += __shfl_xor(sum, off, 16);
    rs[r] = 1.0f / sum;
#pragma unroll
    for (int tc = 0; tc < 4; ++tc)
      Ps[row][16 * tc + lr] = rv ? f2bf(e[tc]) : (u16)0;
  }

  asm volatile("s_waitcnt lgkmcnt(0)" ::: "memory");
  __builtin_amdgcn_sched_barrier(0);

  bf16x8 pf0 = *(const bf16x8*)&Ps[16 * w + lr][lhi * 8];
  bf16x8 pf1 = *(const bf16x8*)&Ps[16 * w + lr][32 + lhi * 8];
  f32x4 oacc[4];
#pragma unroll
  for (int dc = 0; dc < 4; ++dc) {
    oacc[dc] = (f32x4){0.f, 0.f, 0.f, 0.f};
    bf16x8 v0 = *(const bf16x8*)&VTs[16 * dc + lr][lhi * 8];
    bf16x8 v1 = *(const bf16x8*)&VTs[16 * dc + lr][32 + lhi * 8];
    oacc[dc] = __builtin_amdgcn_mfma_f32_16x16x32_bf16(pf0, v0, oacc[dc], 0, 0, 0);
    oacc[dc] = __builtin_amdgcn_mfma_f32_16x16x32_bf16(pf1, v1, oacc[dc], 0, 0, 0);
  }

#pragma unroll
  for (int r = 0; r < 4; ++r) {
    const int row = nrow0 + r;
    if (row < 49) {
#pragma unroll
      for (int dc = 0; dc < 4; ++dc)
        Ps[row][16 * dc + lr] = f2bf(oacc[dc][r] * rs[r]);
    }
  }
  asm volatile("s_waitcnt lgkmcnt(0)" ::: "memory");
  __builtin_amdgcn_sched_barrier(0);

  {
    const int r0 = 16 * w;
    const int r1 = (16 * w + 16 < 49) ? 16 * w + 16 : 49;
    u16* ob = attn_out + (long)(b * 49) * 768 + h * 64;
    for (int it = l; it < (r1 - r0) * 8; it += 64) {
      const int row = r0 + (it >> 3), cc = (it & 7) << 3;
      *(ulonglong2*)&ob[(long)row * 768 + cc] = *(const ulonglong2*)&Ps[row][cc];
    }
    float* pout = prev_out + (long)bh * 2401;
    for (int i = r0 * 49 + l; i < r1 * 49; i += 64) pout[i] = bf2f(SB[i]);
  }
}

// ---------------- launch ----------------
extern "C" void kernel_launch(void* const* d_in, const int* in_sizes, int n_in,
                              void* d_out, int out_size, void* d_ws, size_t ws_size,
                              hipStream_t stream) {
  const float* x = (const float*)d_in[0];
  const float* prev = (const float*)d_in[1];
  const float* qkv_w = (const float*)d_in[2];
  const float* proj_w = (const float*)d_in[3];
  const float* proj_b = (const float*)d_in[4];
  const float* bias_table = (const float*)d_in[5];
  const int* rel_idx = (const int*)d_in[6];

  const int B = in_sizes[0] / (49 * 768);  // 1024
  const int M = B * 49;                    // 50176 = 196*256

  float* out0 = (float*)d_out;             // [M,768]
  float* out1 = out0 + (size_t)M * 768;    // [B,12,49,49]

  char* ws = (char*)d_ws;
  u16* xbf = (u16*)ws;                                     // M*768 bf16 (reused as attn_out)
  u16* qkvbf = (u16*)(ws + (size_t)M * 768 * 2);           // M*2304 bf16
  u16* qkvwT = (u16*)(ws + (size_t)M * 768 * 2 + (size_t)M * 2304 * 2);  // [2304,768]
  u16* projwT = qkvwT + 2304 * 768;                        // [768,768]
  float* biasM = (float*)(projwT + 768 * 768);             // [12,2401]

  prep<<<2048 + 1728 + 576 + 113, 256, 0, stream>>>(
      x, xbf, M * 768 / 4, qkv_w, qkvwT, proj_w, projwT,
      bias_table, rel_idx, biasM);

  gemm256<true><<<(M / 256) * (2304 / 256), 512, 0, stream>>>(
      xbf, qkvwT, qkvbf, nullptr, M, 2304, 768, 2304 / 256);

  attn_kernel<<<B * 12, 256, 0, stream>>>(qkvbf, prev, biasM, out1, xbf);

  gemm256<false><<<(M / 256) * (768 / 256), 512, 0, stream>>>(
      xbf, projwT, out0, proj_b, M, 768, 768, 768 / 256);
}